// Round 10
// baseline (226.777 us; speedup 1.0000x reference)
//
#include <hip/hip_runtime.h>
#include <math.h>

#define DD 64
#define CC 128
#define HH 512
#define BATCH 4096

typedef __attribute__((ext_vector_type(2))) float f32x2;

__device__ __forceinline__ f32x2 splat2(float x) { f32x2 v; v[0] = x; v[1] = x; return v; }

__device__ __forceinline__ float fast_softplus(float x) {
    float t = exp2f(-fabsf(x) * 1.44269504f);
    return fmaxf(x, 0.f) + 0.69314718f * log2f(1.f + t);
}

__device__ __forceinline__ float bcast(float x, int l) {
    return __int_as_float(__builtin_amdgcn_readlane(__float_as_int(x), l));
}

typedef const __attribute__((address_space(1))) void* as1_cptr;
typedef __attribute__((address_space(3))) void* as3_ptr;
__device__ __forceinline__ void glds16(const float* g, float* l) {
    __builtin_amdgcn_global_load_lds((as1_cptr)g, (as3_ptr)l, 16, 0, 0);
}
__device__ __forceinline__ void glds4(const float* g, float* l) {
    __builtin_amdgcn_global_load_lds((as1_cptr)g, (as3_ptr)l, 4, 0, 0);
}

// Single kernel, pure f32. Block = 4 waves x R=4 rows = 16 batch rows;
// grid 256 -> exactly 1 block/CU (no inter-block interference; per-CU L2
// staging traffic halved vs 2-block topologies). Lane l owns hidden units
// 8l..8l+7 (deg=(j%63)+1). ALL per-step data staged in LDS double buffer:
//   floats [0,4608): 9 W2 rows, split-half (elems 8l..8l+3 at +16B*l,
//                    8l+4..8l+7 at +1KB+16B*l) -> conflict-free b128
//   floats [4608,5120): W1[i] feedback row, split-half
//   floats [5120,6272): 9 W3 rows x 128 floats (lane reads +lane, +64+lane:
//                    inherent 2-way = free)
// => zero VMEM on the serial chain; R=4 makes the step body (~1100 issue-cyc
// per wave) long enough to cover contended-L2 staging latency before the
// __syncthreads vmcnt drain. 40 staging ops/step, 10 per wave.
#define W1_SLOT 4608
#define W3_SLOT 5120
#define BUF_F   6272                 // 25088 B per buffer, 2 buffers

__global__ __launch_bounds__(256, 1) void made_sample(
    const float* __restrict__ ctx,   // (B, C)
    const float* __restrict__ eps,   // (B, D)
    const float* __restrict__ W1,    // (D+C, H)
    const float* __restrict__ b1,    // (H)
    const float* __restrict__ W2,    // (H, H)
    const float* __restrict__ b2,    // (H)
    const float* __restrict__ W3,    // (H, 2D)
    const float* __restrict__ b3,    // (2D)
    float* __restrict__ out)         // (B, D)
{
    const int lane  = threadIdx.x & 63;
    const int w     = threadIdx.x >> 6;           // wave 0..3
    const int rbase = blockIdx.x * 16 + w * 4;    // 4 batch rows per wave
    const int jbase = 8 * lane;

    __shared__ float sbuf[2][BUF_F];              // 2 x 24.5 KB

    int deg[8];
    #pragma unroll
    for (int u = 0; u < 8; ++u) deg[u] = (jbase + u) % 63 + 1;

    f32x2 p1[4][4], p2[4][4], acc[4];
    #pragma unroll
    for (int j = 0; j < 4; ++j) {
        f32x2 t1, t2;
        t1[0] = b1[jbase + 2 * j]; t1[1] = b1[jbase + 2 * j + 1];
        t2[0] = b2[jbase + 2 * j]; t2[1] = b2[jbase + 2 * j + 1];
        #pragma unroll
        for (int r = 0; r < 4; ++r) { p1[r][j] = t1; p2[r][j] = t2; }
    }
    #pragma unroll
    for (int r = 0; r < 4; ++r) acc[r] = splat2(0.f);

    float ca[4], cb[4], ep[4];
    #pragma unroll
    for (int r = 0; r < 4; ++r) {
        ca[r] = ctx[(rbase + r) * CC + lane];
        cb[r] = ctx[(rbase + r) * CC + 64 + lane];
        ep[r] = eps[(rbase + r) * DD + lane];
    }
    const float b3m = b3[lane];
    const float b3p = b3[64 + lane];

    // ctx chunk ch: f32 W1 rows DD+8ch..+7 -> W2 area slots 0..7 (16 ops/4 waves)
    auto stage_ctx = [&](int ch, float* buf) {
        #pragma unroll
        for (int o4 = 0; o4 < 4; ++o4) {
            const int o = 4 * o4 + w;            // 0..15
            const int q = o >> 1, hf = o & 1;
            glds16(W1 + (DD + 8 * ch + q) * HH + lane * 8 + hf * 4,
                   buf + q * 512 + hf * 256);
        }
    };
    // step `in`: 40 ops (10/wave): 9 W2 rows (18 glds16) + 9 W3 rows (18 glds4)
    // + W1 row (2 glds16) + 2 duplicate-pad W1 ops.
    auto stage_step = [&](int in, float* buf) {
        const int basen = (in == 0) ? 0 : (in - 1);
        #pragma unroll
        for (int o10 = 0; o10 < 10; ++o10) {
            const int o = 4 * o10 + w;           // 0..39
            if (o < 18) {
                const int t = o >> 1, hf = o & 1;
                int k = basen + 63 * t;
                if (k >= HH) k = HH - 1;         // t=8 OOB: mult zeroed in compute
                glds16(W2 + k * HH + lane * 8 + hf * 4, buf + t * 512 + hf * 256);
            } else if (o < 36) {
                const int u2 = o - 18, t = u2 >> 1, hf = u2 & 1;
                int k = basen + 63 * t;
                if (k >= HH) k = HH - 1;
                glds4(W3 + k * (2 * DD) + hf * 64 + lane,
                      buf + W3_SLOT + t * 128 + hf * 64);
            } else {
                const int hf = o & 1;            // 36,37 + duplicates 38,39
                glds16(W1 + in * HH + lane * 8 + hf * 4, buf + W1_SLOT + hf * 256);
            }
        }
    };

    // ---- context init: pre1 += ctx @ W1[D:,:], 16 chunks of 8 rows ----
    stage_ctx(0, sbuf[0]);
    __syncthreads();
    #pragma unroll 1
    for (int ch = 0; ch < 16; ++ch) {
        float* cur = sbuf[ch & 1];
        if (ch < 15) stage_ctx(ch + 1, sbuf[(ch + 1) & 1]);
        else         stage_step(0, sbuf[0]);     // 16&1==0: step-0 parity OK
        #pragma unroll
        for (int q = 0; q < 8; ++q) {
            f32x2 wv[4];
            {
                float4 a = *(const float4*)(cur + q * 512 + lane * 4);
                float4 b = *(const float4*)(cur + q * 512 + 256 + lane * 4);
                wv[0][0] = a.x; wv[0][1] = a.y; wv[1][0] = a.z; wv[1][1] = a.w;
                wv[2][0] = b.x; wv[2][1] = b.y; wv[3][0] = b.z; wv[3][1] = b.w;
            }
            const int c = 8 * ch + q;
            #pragma unroll
            for (int r = 0; r < 4; ++r) {
                const f32x2 cv = splat2(bcast((ch < 8) ? ca[r] : cb[r], c & 63));
                #pragma unroll
                for (int j = 0; j < 4; ++j) p1[r][j] += cv * wv[j];
            }
        }
        __syncthreads();
    }

    float z[4] = {0.f, 0.f, 0.f, 0.f};

    // ---- autoregressive main loop ----
    #pragma unroll 1
    for (int i = 0; i < DD; ++i) {
        float* cur = sbuf[i & 1];
        if (i < 63) stage_step(i + 1, sbuf[(i + 1) & 1]);

        const int base = (i == 0) ? 0 : (i - 1);
        const float vm8 = (i <= 8) ? 1.f : 0.f;  // t=8 validity; bcast lane 63

        // LDS preloads off the serial chain
        f32x2 w1v[4];
        {
            float4 a = *(const float4*)(cur + W1_SLOT + lane * 4);
            float4 b = *(const float4*)(cur + W1_SLOT + 256 + lane * 4);
            w1v[0][0] = a.x; w1v[0][1] = a.y; w1v[1][0] = a.z; w1v[1][1] = a.w;
            w1v[2][0] = b.x; w1v[2][1] = b.y; w1v[3][0] = b.z; w1v[3][1] = b.w;
        }
        f32x2 w3v[9];
        #pragma unroll
        for (int t = 0; t < 9; ++t) {
            w3v[t][0] = cur[W3_SLOT + t * 128 + lane];
            w3v[t][1] = cur[W3_SLOT + t * 128 + 64 + lane];
        }

        // (a) finalized h1 (deg==i); zero at i==0. cmp shared across rows.
        float m[4] = {0.f, 0.f, 0.f, 0.f};
        #pragma unroll
        for (int u = 0; u < 8; ++u) {
            const bool hit = (deg[u] == i);
            #pragma unroll
            for (int r = 0; r < 4; ++r)
                m[r] = hit ? p1[r][u >> 1][u & 1] : m[r];
        }
        #pragma unroll
        for (int r = 0; r < 4; ++r) m[r] = fmaxf(m[r], 0.f);

        // (b) rank-9 update of pre2 from staged W2 rows
        #pragma unroll
        for (int t = 0; t < 9; ++t) {
            f32x2 wv[4];
            {
                float4 a = *(const float4*)(cur + t * 512 + lane * 4);
                float4 b = *(const float4*)(cur + t * 512 + 256 + lane * 4);
                wv[0][0] = a.x; wv[0][1] = a.y; wv[1][0] = a.z; wv[1][1] = a.w;
                wv[2][0] = b.x; wv[2][1] = b.y; wv[3][0] = b.z; wv[3][1] = b.w;
            }
            const int ln = (t == 8) ? 63 : ((base + 63 * t) >> 3);
            #pragma unroll
            for (int r = 0; r < 4; ++r) {
                float h = bcast(m[r], ln);
                if (t == 8) h *= vm8;
                const f32x2 hv = splat2(h);
                #pragma unroll
                for (int j = 0; j < 4; ++j) p2[r][j] += hv * wv[j];
            }
        }

        // (c) newly-final h2 (deg==i)
        float hn[4] = {0.f, 0.f, 0.f, 0.f};
        #pragma unroll
        for (int u = 0; u < 8; ++u) {
            const bool hit = (deg[u] == i);
            #pragma unroll
            for (int r = 0; r < 4; ++r)
                hn[r] = hit ? p2[r][u >> 1][u & 1] : hn[r];
        }
        #pragma unroll
        for (int r = 0; r < 4; ++r) hn[r] = fmaxf(hn[r], 0.f);

        // (d) incremental output acc from staged W3 rows
        #pragma unroll
        for (int t = 0; t < 9; ++t) {
            const int ln = (t == 8) ? 63 : ((base + 63 * t) >> 3);
            #pragma unroll
            for (int r = 0; r < 4; ++r) {
                float h = bcast(hn[r], ln);
                if (t == 8) h *= vm8;
                acc[r] += splat2(h) * w3v[t];
            }
        }

        // (e) z_i: column i's totals live in lane i
        #pragma unroll
        for (int r = 0; r < 4; ++r) {
            const float am = acc[r][0] + b3m;
            const float ap = acc[r][1] + b3p;
            const float sp = fast_softplus(ap);
            const float zc = fmaf(sp, ep[r], am);
            const float zi = bcast(zc, i);
            if (lane == i) z[r] = zi;
            const f32x2 zi2 = splat2(zi);
            #pragma unroll
            for (int j = 0; j < 4; ++j) p1[r][j] += zi2 * w1v[j];
        }

        __syncthreads();
    }

    #pragma unroll
    for (int r = 0; r < 4; ++r) out[(rbase + r) * DD + lane] = z[r];
}

extern "C" void kernel_launch(void* const* d_in, const int* in_sizes, int n_in,
                              void* d_out, int out_size, void* d_ws, size_t ws_size,
                              hipStream_t stream) {
    const float* ctx = (const float*)d_in[0];
    const float* eps = (const float*)d_in[1];
    const float* W1  = (const float*)d_in[2];
    const float* b1  = (const float*)d_in[3];
    const float* W2  = (const float*)d_in[4];
    const float* b2  = (const float*)d_in[5];
    const float* W3  = (const float*)d_in[6];
    const float* b3  = (const float*)d_in[7];
    (void)d_ws; (void)ws_size; (void)in_sizes; (void)n_in; (void)out_size;

    made_sample<<<BATCH / 16, 256, 0, stream>>>(ctx, eps, W1, b1, W2, b2, W3, b3,
                                                (float*)d_out);
}

// Round 11
// 191.402 us; speedup vs baseline: 1.1848x; 1.1848x over previous
//
#include <hip/hip_runtime.h>
#include <math.h>

#define DD 64
#define CC 128
#define HH 512
#define BATCH 4096

typedef __attribute__((ext_vector_type(2))) float f32x2;

__device__ __forceinline__ f32x2 splat2(float x) { f32x2 v; v[0] = x; v[1] = x; return v; }

__device__ __forceinline__ float fast_softplus(float x) {
    float t = exp2f(-fabsf(x) * 1.44269504f);
    return fmaxf(x, 0.f) + 0.69314718f * log2f(1.f + t);
}

__device__ __forceinline__ float bcast(float x, int l) {
    return __int_as_float(__builtin_amdgcn_readlane(__float_as_int(x), l));
}

typedef const __attribute__((address_space(1))) void* as1_cptr;
typedef __attribute__((address_space(3))) void* as3_ptr;
__device__ __forceinline__ void glds16(const float* g, float* l) {
    __builtin_amdgcn_global_load_lds((as1_cptr)g, (as3_ptr)l, 16, 0, 0);
}

#define ROWF 512                 // floats per LDS row slot
#define BUF_F (9 * ROWF)         // 4608 floats = 18 KB per buffer

// R6 structure (grid 512, 4 waves x R=2, split-half conflict-free LDS, f32)
// with a restructured K-loop:
//  * TRIPLE-buffered W2 staging, prefetch depth 2: stage(i+2) issued at top of
//    step i (20 glds/block, uniform 5/wave).
//  * Barrier WITHOUT vmcnt(0) drain: end-of-step does s_waitcnt vmcnt(5)
//    lgkmcnt(0) + raw s_barrier. The 5 newest vmem ops are this step's own
//    staging (glds builtins keep program order), so stage(i+2) stays in
//    flight across the barrier while stage(i+1) — needed next step — is
//    provably retired, regardless of where the compiler places plain loads.
//  * W3 rows + W1[i] feedback row register-prefetched one step ahead
//    (unroll-2 slot rotation) — no VMEM consumption on the serial chain.
// Buffer schedule: step i reads sbuf[(i+1)%3]; stage(i+2) -> sbuf[(i+3)%3].
// Ctx phase keeps full __syncthreads (one-time cost) and pre-stages steps
// 0 (-> buf1, at ch14) and 1 (-> buf2, at ch15).
__global__ __launch_bounds__(256, 2) void made_sample(
    const float* __restrict__ ctx,   // (B, C)
    const float* __restrict__ eps,   // (B, D)
    const float* __restrict__ W1,    // (D+C, H)
    const float* __restrict__ b1,    // (H)
    const float* __restrict__ W2,    // (H, H)
    const float* __restrict__ b2,    // (H)
    const float* __restrict__ W3,    // (H, 2D)
    const float* __restrict__ b3,    // (2D)
    float* __restrict__ out)         // (B, D)
{
    const int lane  = threadIdx.x & 63;
    const int w     = threadIdx.x >> 6;          // wave 0..3
    const int rbase = blockIdx.x * 8 + w * 2;    // 2 batch rows per wave
    const int jbase = 8 * lane;

    __shared__ float sbuf[3][BUF_F];             // 3 x 18 KB

    int deg[8];
    #pragma unroll
    for (int u = 0; u < 8; ++u) deg[u] = (jbase + u) % 63 + 1;

    // split-half LDS read: slot base -> 4 f32x2 for this lane (conflict-free)
    auto ldrow = [&](const float* base_, f32x2* r_) {
        float4 a = *(const float4*)(base_ + lane * 4);
        float4 b = *(const float4*)(base_ + 256 + lane * 4);
        r_[0][0] = a.x; r_[0][1] = a.y; r_[1][0] = a.z; r_[1][1] = a.w;
        r_[2][0] = b.x; r_[2][1] = b.y; r_[3][0] = b.z; r_[3][1] = b.w;
    };

    f32x2 p1[2][4], p2[2][4], acc[2];
    #pragma unroll
    for (int j = 0; j < 4; ++j) {
        f32x2 t1, t2;
        t1[0] = b1[jbase + 2 * j]; t1[1] = b1[jbase + 2 * j + 1];
        t2[0] = b2[jbase + 2 * j]; t2[1] = b2[jbase + 2 * j + 1];
        p1[0][j] = t1; p1[1][j] = t1;
        p2[0][j] = t2; p2[1][j] = t2;
    }
    acc[0] = splat2(0.f);
    acc[1] = splat2(0.f);

    float ca[2], cb[2], ep[2];
    #pragma unroll
    for (int r = 0; r < 2; ++r) {
        ca[r] = ctx[(rbase + r) * CC + lane];
        cb[r] = ctx[(rbase + r) * CC + 64 + lane];
        ep[r] = eps[(rbase + r) * DD + lane];
    }
    const float b3m = b3[lane];
    const float b3p = b3[64 + lane];

    // ctx chunk ch: W1 rows DD+8ch..+7 -> slots 0..7 (16 glds, 4/wave uniform)
    auto stage_ctx = [&](int ch, float* buf) {
        #pragma unroll
        for (int q4 = 0; q4 < 4; ++q4) {
            const int o = 4 * q4 + w;            // 0..15
            const int q = o >> 1, hf = o & 1;
            glds16(W1 + (DD + 8 * ch + q) * HH + lane * 8 + hf * 4,
                   buf + q * ROWF + hf * 256);
        }
    };
    // step `in`: 9 W2 rows (18 glds) + 2 duplicate t=8 ops -> 20, 5/wave uniform
    auto stage_step = [&](int in, float* buf) {
        const int basen = (in == 0) ? 0 : (in - 1);
        #pragma unroll
        for (int q5 = 0; q5 < 5; ++q5) {
            const int o = 4 * q5 + w;            // 0..19
            const int oc = (o < 18) ? o : (o - 2);
            const int t = oc >> 1, hf = oc & 1;
            int k = basen + 63 * t;
            if (k >= HH) k = HH - 1;             // OOB t=8: mult zeroed in compute
            glds16(W2 + k * HH + lane * 8 + hf * 4, buf + t * ROWF + hf * 256);
        }
    };
    // W3 rows + W1 feedback row for step `in`, direct to registers
    auto loadW3W1 = [&](int in, f32x2* w3v, f32x2* w1v) {
        const int basen = (in == 0) ? 0 : (in - 1);
        #pragma unroll
        for (int t = 0; t < 9; ++t) {
            int k = basen + 63 * t;
            if (k >= HH) k = HH - 1;
            w3v[t][0] = W3[k * (2 * DD) + lane];
            w3v[t][1] = W3[k * (2 * DD) + 64 + lane];
        }
        float4 a = *(const float4*)(W1 + in * HH + lane * 8);
        float4 b = *(const float4*)(W1 + in * HH + lane * 8 + 4);
        w1v[0][0] = a.x; w1v[0][1] = a.y; w1v[1][0] = a.z; w1v[1][1] = a.w;
        w1v[2][0] = b.x; w1v[2][1] = b.y; w1v[3][0] = b.z; w1v[3][1] = b.w;
    };

    // ---- context init: pre1 += ctx @ W1[D:,:], 16 chunks, %3 buffers ----
    stage_ctx(0, &sbuf[0][0]);
    __syncthreads();
    #pragma unroll 1
    for (int ch = 0; ch < 16; ++ch) {
        float* cur = &sbuf[ch % 3][0];
        if (ch < 15)  stage_ctx(ch + 1, &sbuf[(ch + 1) % 3][0]);
        if (ch == 14) stage_step(0, &sbuf[1][0]);   // buf1 free after ch13
        if (ch == 15) stage_step(1, &sbuf[2][0]);   // buf2 free after ch14
        #pragma unroll
        for (int q = 0; q < 8; ++q) {
            f32x2 wv[4];
            ldrow(cur + q * ROWF, wv);
            const int c = 8 * ch + q;
            #pragma unroll
            for (int r = 0; r < 2; ++r) {
                const f32x2 cv = splat2(bcast((ch < 8) ? ca[r] : cb[r], c & 63));
                #pragma unroll
                for (int j = 0; j < 4; ++j) p1[r][j] += cv * wv[j];
            }
        }
        __syncthreads();
    }

    f32x2 w3s[2][9], w1s[2][4];
    loadW3W1(0, w3s[0], w1s[0]);
    float z[2] = {0.f, 0.f};

    // ---- autoregressive main loop (raw-barrier pipeline) ----
    #pragma unroll 2
    for (int i = 0; i < DD; ++i) {
        const int cs = i & 1;
        float* cur = &sbuf[(i + 1) % 3][0];
        if (i < 63) {
            loadW3W1(i + 1, w3s[cs ^ 1], w1s[cs ^ 1]);  // reg prefetch, depth 1
            stage_step(i + 2, &sbuf[(i + 3) % 3][0]);   // LDS prefetch, depth 2
        }
        const int base = (i == 0) ? 0 : (i - 1);
        const float vm8 = (base + 504 < HH) ? 1.f : 0.f;

        // (a) finalized h1 (deg==i); zero at i==0
        float m0 = 0.f, m1 = 0.f;
        #pragma unroll
        for (int u = 0; u < 8; ++u) {
            const bool hit = (deg[u] == i);
            m0 = hit ? p1[0][u >> 1][u & 1] : m0;
            m1 = hit ? p1[1][u >> 1][u & 1] : m1;
        }
        m0 = fmaxf(m0, 0.f);
        m1 = fmaxf(m1, 0.f);

        // (b) rank-9 update of pre2 from staged W2 rows
        #pragma unroll
        for (int t = 0; t < 9; ++t) {
            f32x2 wv[4];
            ldrow(cur + t * ROWF, wv);
            const int ln = (t == 8) ? 63 : ((base + 63 * t) >> 3);
            float h0 = bcast(m0, ln), h1 = bcast(m1, ln);
            if (t == 8) { h0 *= vm8; h1 *= vm8; }
            const f32x2 h0v = splat2(h0), h1v = splat2(h1);
            #pragma unroll
            for (int j = 0; j < 4; ++j) {
                p2[0][j] += h0v * wv[j];
                p2[1][j] += h1v * wv[j];
            }
        }

        // (c) newly-final h2 (deg==i)
        float hn0 = 0.f, hn1 = 0.f;
        #pragma unroll
        for (int u = 0; u < 8; ++u) {
            const bool hit = (deg[u] == i);
            hn0 = hit ? p2[0][u >> 1][u & 1] : hn0;
            hn1 = hit ? p2[1][u >> 1][u & 1] : hn1;
        }
        hn0 = fmaxf(hn0, 0.f);
        hn1 = fmaxf(hn1, 0.f);

        // (d) incremental output acc from register-prefetched W3 rows
        #pragma unroll
        for (int t = 0; t < 9; ++t) {
            const int ln = (t == 8) ? 63 : ((base + 63 * t) >> 3);
            float h0 = bcast(hn0, ln), h1 = bcast(hn1, ln);
            if (t == 8) { h0 *= vm8; h1 *= vm8; }
            acc[0] += splat2(h0) * w3s[cs][t];
            acc[1] += splat2(h1) * w3s[cs][t];
        }

        // (e) z_i: column i's totals live in lane i
        #pragma unroll
        for (int r = 0; r < 2; ++r) {
            const float am = acc[r][0] + b3m;
            const float ap = acc[r][1] + b3p;
            const float sp = fast_softplus(ap);
            const float zc = fmaf(sp, ep[r], am);
            const float zi = bcast(zc, i);
            if (lane == i) z[r] = zi;
            const f32x2 zi2 = splat2(zi);
            #pragma unroll
            for (int j = 0; j < 4; ++j) p1[r][j] += zi2 * w1s[cs][j];
        }

        if (i < 63) {
            // vmcnt(5): retire all but this step's own 5 staging ops ->
            // stage(i+1) provably landed; stage(i+2) stays in flight.
            __builtin_amdgcn_s_waitcnt(0x0075);   // vmcnt(5) expcnt(7) lgkmcnt(0)
            __builtin_amdgcn_s_barrier();
        }
    }

    #pragma unroll
    for (int r = 0; r < 2; ++r) out[(rbase + r) * DD + lane] = z[r];
}

extern "C" void kernel_launch(void* const* d_in, const int* in_sizes, int n_in,
                              void* d_out, int out_size, void* d_ws, size_t ws_size,
                              hipStream_t stream) {
    const float* ctx = (const float*)d_in[0];
    const float* eps = (const float*)d_in[1];
    const float* W1  = (const float*)d_in[2];
    const float* b1  = (const float*)d_in[3];
    const float* W2  = (const float*)d_in[4];
    const float* b2  = (const float*)d_in[5];
    const float* W3  = (const float*)d_in[6];
    const float* b3  = (const float*)d_in[7];
    (void)d_ws; (void)ws_size; (void)in_sizes; (void)n_in; (void)out_size;

    made_sample<<<BATCH / 8, 256, 0, stream>>>(ctx, eps, W1, b1, W2, b2, W3, b3,
                                               (float*)d_out);
}